// Round 7
// baseline (96.149 us; speedup 1.0000x reference)
//
#include <hip/hip_runtime.h>
#include <hip/hip_bf16.h>

// ParameterMixture as a thin GEMM on the matrix cores (single fused kernel):
//   C[32 x 1M] = P[32 x 64] @ W[64 x 1M]  (W = wbank viewed [E, O*I])
// v_mfma_f32_32x32x16_bf16 with split compensation:
//   P = Ph+Pl, W = Wh+Wl (bf16);  C ~= Ph*Wh + Ph*Wl + Pl*Wh   (verified R6)
// Per-lane A-fragments computed in registers (no helper kernel, no LDS).
// Each wave streams 64 expert rows x 256 contiguous cols (8 steps x 128 B),
// accumulating via 12 MFMA/step. Output written with non-temporal stores so
// the 128 MB of C does not evict wbank from L2/L3 (wbank ~= L3 size).
//
// Layouts (gfx950, 32x32x16 bf16, verified by R6 pass @ absmax 9.8e-4):
//   A: row = lane&31, k = 8*(lane>>5)+j
//   B: col = lane&31, k = 8*(lane>>5)+j
//   C: col = lane&31, row = (reg&3) + 8*(reg>>2) + 4*(lane>>5)

typedef __attribute__((ext_vector_type(8)))  short short8v;
typedef __attribute__((ext_vector_type(16))) float f32x16;

constexpr int E = 64;
constexpr int K = 8;
constexpr int B = 32;
constexpr int IN_DIM = 1024;
constexpr int OUT_DIM = 1024;

constexpr int NCOL     = OUT_DIM * IN_DIM;    // 1,048,576
constexpr int BLK      = 256;
constexpr int GRID     = 1024;                // 4 blocks/CU, single round
constexpr int WAVES    = GRID * 4;            // 4096
constexpr int STEPS    = NCOL / 32 / WAVES;   // 8 (exact)
constexpr int WM_ELEMS = B * NCOL;
constexpr int OB4      = OUT_DIM / 4;         // 256

__global__ __launch_bounds__(BLK, 4) void ParameterMixture_86835648790543_kernel(
    const float* __restrict__ wprobs,   // [B,K]
    const float* __restrict__ bprobs,   // [B,K]
    const int*   __restrict__ widx,     // [B,K]
    const int*   __restrict__ bidx,     // [B,K]
    const float* __restrict__ wbank,    // [E, NCOL]
    const float* __restrict__ bbank,    // [E,O]
    float*       __restrict__ out)      // [B*NCOL] ++ [B*O]
{
    const int bid  = blockIdx.x;
    const int t    = threadIdx.x;
    const int wv   = t >> 6;
    const int lane = t & 63;
    const int m    = lane & 31;         // A row (batch) this lane covers
    const int kh   = (lane >> 5) * 8;   // k half-offset
    const int cl   = lane & 31;         // B/C column within group

    // ---- bias prologue on blocks 0..31 (tiny, fp32 exact) ----
    if (bid < 32) {
        const int tt   = bid * BLK + t;     // float4 idx into [B,O]
        const int b    = tt / OB4;
        const int off4 = tt % OB4;
        const float4* __restrict__ bb4 = (const float4*)bbank;
        float4 a4 = make_float4(0.f, 0.f, 0.f, 0.f);
#pragma unroll
        for (int k = 0; k < K; ++k) {
            const float p = bprobs[b * K + k];
            const int   e = bidx[b * K + k];
            const float4 v = bb4[e * OB4 + off4];
            a4.x += p * v.x; a4.y += p * v.y;
            a4.z += p * v.z; a4.w += p * v.w;
        }
        ((float4*)(out + WM_ELEMS))[tt] = a4;
    }

    // ---- per-lane A-fragments (P in bf16 hi/lo, MFMA layout) ----
    float wp[K];
    int   wi[K];
#pragma unroll
    for (int k2 = 0; k2 < K; ++k2) {
        wp[k2] = wprobs[m * K + k2];
        wi[k2] = widx[m * K + k2];
    }
    short8v aH[4], aL[4];
#pragma unroll
    for (int s = 0; s < 4; ++s) {
#pragma unroll
        for (int j = 0; j < 8; ++j) {
            const int e = s * 16 + kh + j;
            float p = 0.f;
#pragma unroll
            for (int k2 = 0; k2 < K; ++k2)
                p += (wi[k2] == e) ? wp[k2] : 0.f;
            const __hip_bfloat16 h  = __float2bfloat16(p);
            const float          hf = __bfloat162float(h);
            const __hip_bfloat16 l  = __float2bfloat16(p - hf);
            aH[s][j] = __builtin_bit_cast(short, h);
            aL[s][j] = __builtin_bit_cast(short, l);
        }
    }

    const size_t ncol    = (size_t)NCOL;
    const int    wave_id = bid * 4 + wv;

#pragma unroll 1
    for (int step = 0; step < STEPS; ++step) {
        // contiguous per-wave stepping: 8 consecutive 128B lines per row
        const int col0 = wave_id * (32 * STEPS) + step * 32;
        const float* __restrict__ wcol = wbank + col0 + cl;

        // 32 column-mode dword loads, all in flight together
        float w[4][8];
#pragma unroll
        for (int s = 0; s < 4; ++s)
#pragma unroll
            for (int j = 0; j < 8; ++j)
                w[s][j] = wcol[(size_t)(s * 16 + kh + j) * ncol];

        f32x16 acc;
#pragma unroll
        for (int i = 0; i < 16; ++i) acc[i] = 0.f;

#pragma unroll
        for (int s = 0; s < 4; ++s) {
            short8v bh, bl;
#pragma unroll
            for (int j = 0; j < 8; ++j) {
                const float x = w[s][j];
                const __hip_bfloat16 h  = __float2bfloat16(x);
                const float          hf = __bfloat162float(h);
                const __hip_bfloat16 l  = __float2bfloat16(x - hf);
                bh[j] = __builtin_bit_cast(short, h);
                bl[j] = __builtin_bit_cast(short, l);
            }
            acc = __builtin_amdgcn_mfma_f32_32x32x16_bf16(aH[s], bh, acc, 0, 0, 0);
            acc = __builtin_amdgcn_mfma_f32_32x32x16_bf16(aH[s], bl, acc, 0, 0, 0);
            acc = __builtin_amdgcn_mfma_f32_32x32x16_bf16(aL[s], bh, acc, 0, 0, 0);
        }

        // C-tile store, non-temporal (don't evict wbank from L2/L3)
        float* __restrict__ ob = out + (size_t)((lane >> 5) * 4) * ncol + col0 + cl;
#pragma unroll
        for (int reg = 0; reg < 16; ++reg) {
            const int row = (reg & 3) + 8 * (reg >> 2);
            __builtin_nontemporal_store(acc[reg], ob + (size_t)row * ncol);
        }
    }
}

extern "C" void kernel_launch(void* const* d_in, const int* in_sizes, int n_in,
                              void* d_out, int out_size, void* d_ws, size_t ws_size,
                              hipStream_t stream) {
    const float* wprobs = (const float*)d_in[0];
    const float* bprobs = (const float*)d_in[1];
    const int*   widx   = (const int*)d_in[2];
    const int*   bidx   = (const int*)d_in[3];
    const float* wbank  = (const float*)d_in[4];
    const float* bbank  = (const float*)d_in[5];
    float*       out    = (float*)d_out;

    ParameterMixture_86835648790543_kernel<<<GRID, BLK, 0, stream>>>(
        wprobs, bprobs, widx, bidx, wbank, bbank, out);
}

// Round 9
// 93.747 us; speedup vs baseline: 1.0256x; 1.0256x over previous
//
#include <hip/hip_runtime.h>
#include <hip/hip_bf16.h>

// ParameterMixture as a thin GEMM on matrix cores, float4-wide streams:
//   C[32 x 1M] = P[32 x 64] @ W[64 x 1M]   (W = wbank viewed [E, O*I])
// v_mfma_f32_32x32x16_bf16 + split compensation (Ph*Wh + Ph*Wl + Pl*Wh),
// verified R6/R7 (absmax 9.8e-4 vs 4.57e-3 threshold).
//
// R8/R9: dwordx4 column loads. Lane cl loads cols 4cl..4cl+3 per expert
// row -> each half-wave reads 512B CONTIGUOUS per row (was 128B). The 4
// elements feed 4 MFMA tiles over strided col sets {4c+t}; tile t's col
// 4c+t lives in element t of lane c, so no cross-lane redistribution is
// needed, and at store time lane c holds cols 4c..4c+3 of each C row in
// its 4 accumulators -> direct dwordx4 stores (512B runs on writes too).
// 4x fewer VMEM instructions, 4x longer DRAM runs.
//
// Layouts (gfx950, 32x32x16 bf16):
//   A: row = lane&31, k = 8*(lane>>5)+j       B: col = lane&31, same k
//   C: col = lane&31, row = (reg&3) + 8*(reg>>2) + 4*(lane>>5)

typedef __attribute__((ext_vector_type(8)))  short short8v;
typedef __attribute__((ext_vector_type(16))) float f32x16;

constexpr int E = 64;
constexpr int K = 8;
constexpr int B = 32;
constexpr int IN_DIM = 1024;
constexpr int OUT_DIM = 1024;

constexpr int NCOL     = OUT_DIM * IN_DIM;    // 1,048,576
constexpr int BLK      = 256;
constexpr int GRID     = 512;                 // 2 blocks/CU, single round
constexpr int WAVES    = GRID * 4;            // 2048
constexpr int CPW      = NCOL / WAVES;        // 512 cols per wave
constexpr int CSTEP    = 128;                 // cols per step
constexpr int STEPS    = CPW / CSTEP;         // 4
constexpr int NRG      = STEPS * 4;           // 16 rowgroups total per wave
constexpr int WM_ELEMS = B * NCOL;
constexpr int OB4      = OUT_DIM / 4;         // 256

struct HL { short h; short l; };

__device__ __forceinline__ HL split_bf16(float x) {
    const __hip_bfloat16 hb = __float2bfloat16(x);
    const float          hf = __bfloat162float(hb);
    const __hip_bfloat16 lb = __float2bfloat16(x - hf);
    HL r;
    r.h = __builtin_bit_cast(short, hb);
    r.l = __builtin_bit_cast(short, lb);
    return r;
}

__global__ __launch_bounds__(BLK, 2) void ParameterMixture_86835648790543_kernel(
    const float* __restrict__ wprobs,   // [B,K]
    const float* __restrict__ bprobs,   // [B,K]
    const int*   __restrict__ widx,     // [B,K]
    const int*   __restrict__ bidx,     // [B,K]
    const float* __restrict__ wbank,    // [E, NCOL]
    const float* __restrict__ bbank,    // [E,O]
    float*       __restrict__ out)      // [B*NCOL] ++ [B*O]
{
    const int bid  = blockIdx.x;
    const int t    = threadIdx.x;
    const int wv   = t >> 6;
    const int lane = t & 63;
    const int m    = lane & 31;         // A row (batch)
    const int kh   = (lane >> 5) * 8;   // k half-offset
    const int cl   = lane & 31;         // column-group index

    // ---- bias prologue on blocks 0..31 (tiny, fp32 exact) ----
    if (bid < 32) {
        const int tt   = bid * BLK + t;
        const int b    = tt / OB4;
        const int off4 = tt % OB4;
        const float4* __restrict__ bb4 = (const float4*)bbank;
        float4 a4 = make_float4(0.f, 0.f, 0.f, 0.f);
#pragma unroll
        for (int k = 0; k < K; ++k) {
            const float p = bprobs[b * K + k];
            const int   e = bidx[b * K + k];
            const float4 v = bb4[e * OB4 + off4];
            a4.x += p * v.x; a4.y += p * v.y;
            a4.z += p * v.z; a4.w += p * v.w;
        }
        ((float4*)(out + WM_ELEMS))[tt] = a4;
    }

    // ---- per-lane A-fragments (P in bf16 hi/lo, MFMA layout) ----
    float wp[K];
    int   wi[K];
#pragma unroll
    for (int k2 = 0; k2 < K; ++k2) {
        wp[k2] = wprobs[m * K + k2];
        wi[k2] = widx[m * K + k2];
    }
    short8v aH[4], aL[4];
#pragma unroll
    for (int s = 0; s < 4; ++s) {
#pragma unroll
        for (int j = 0; j < 8; ++j) {
            const int e = s * 16 + kh + j;
            float p = 0.f;
#pragma unroll
            for (int k2 = 0; k2 < K; ++k2)
                p += (wi[k2] == e) ? wp[k2] : 0.f;
            const HL r = split_bf16(p);
            aH[s][j] = r.h;
            aL[s][j] = r.l;
        }
    }

    const size_t ncol     = (size_t)NCOL;
    const int    wave_id  = bid * 4 + wv;
    const int    col_base = wave_id * CPW;

    // rowgroup g (0..NRG-1): step = g>>2, rows (g&3)*16 + kh + j, 8 float4 loads
    auto load_rg = [&](float4 (&w)[8], int g) {
        if (g > NRG - 1) g = NRG - 1;                 // tail clamp (harmless re-read)
        const int c0 = col_base + (g >> 2) * CSTEP + 4 * cl;
        const int r0 = (g & 3) * 16 + kh;
        const float* __restrict__ base = wbank + c0;
#pragma unroll
        for (int j = 0; j < 8; ++j)
            w[j] = *(const float4*)(base + (size_t)(r0 + j) * ncol);
    };

    float4 bufA[8], bufB[8];
    load_rg(bufA, 0);
    load_rg(bufB, 1);

#pragma unroll 1
    for (int step = 0; step < STEPS; ++step) {
        f32x16 acc[4];
#pragma unroll
        for (int tt2 = 0; tt2 < 4; ++tt2)
#pragma unroll
            for (int i = 0; i < 16; ++i) acc[tt2][i] = 0.f;

        const int g0 = step * 4;

        // one rowgroup: cvt 32 floats -> 4 tiles' bh/bl, then 12 MFMA
        auto compute_rg = [&](const float4 (&w)[8], int rg) {
            short8v bh[4], bl[4];
#pragma unroll
            for (int j = 0; j < 8; ++j) {
                const HL rx = split_bf16(w[j].x);
                const HL ry = split_bf16(w[j].y);
                const HL rz = split_bf16(w[j].z);
                const HL rw = split_bf16(w[j].w);
                bh[0][j] = rx.h; bl[0][j] = rx.l;
                bh[1][j] = ry.h; bl[1][j] = ry.l;
                bh[2][j] = rz.h; bl[2][j] = rz.l;
                bh[3][j] = rw.h; bl[3][j] = rw.l;
            }
#pragma unroll
            for (int tt2 = 0; tt2 < 4; ++tt2) {
                acc[tt2] = __builtin_amdgcn_mfma_f32_32x32x16_bf16(aH[rg], bh[tt2], acc[tt2], 0, 0, 0);
                acc[tt2] = __builtin_amdgcn_mfma_f32_32x32x16_bf16(aH[rg], bl[tt2], acc[tt2], 0, 0, 0);
                acc[tt2] = __builtin_amdgcn_mfma_f32_32x32x16_bf16(aL[rg], bh[tt2], acc[tt2], 0, 0, 0);
            }
        };

        compute_rg(bufA, 0);  load_rg(bufA, g0 + 2);
        compute_rg(bufB, 1);  load_rg(bufB, g0 + 3);
        compute_rg(bufA, 2);  load_rg(bufA, g0 + 4);   // next step's rg0
        compute_rg(bufB, 3);  load_rg(bufB, g0 + 5);   // next step's rg1

        // store: lane cl holds cols c0+4cl..+3 of each row in its 4 accs
        const int c0 = col_base + step * CSTEP + 4 * cl;
        float* __restrict__ ob = out + c0 + (size_t)((lane >> 5) * 4) * ncol;
#pragma unroll
        for (int reg = 0; reg < 16; ++reg) {
            const int row = (reg & 3) + 8 * (reg >> 2);
            const float4 v = make_float4(acc[0][reg], acc[1][reg], acc[2][reg], acc[3][reg]);
            *(float4*)(ob + (size_t)row * ncol) = v;
        }
    }
}

extern "C" void kernel_launch(void* const* d_in, const int* in_sizes, int n_in,
                              void* d_out, int out_size, void* d_ws, size_t ws_size,
                              hipStream_t stream) {
    const float* wprobs = (const float*)d_in[0];
    const float* bprobs = (const float*)d_in[1];
    const int*   widx   = (const int*)d_in[2];
    const int*   bidx   = (const int*)d_in[3];
    const float* wbank  = (const float*)d_in[4];
    const float* bbank  = (const float*)d_in[5];
    float*       out    = (float*)d_out;

    ParameterMixture_86835648790543_kernel<<<GRID, BLK, 0, stream>>>(
        wprobs, bprobs, widx, bidx, wbank, bbank, out);
}